// Round 5
// baseline (324.861 us; speedup 1.0000x reference)
//
#include <hip/hip_runtime.h>
#include <math.h>

// Problem constants
#define TT 4096
#define DD 512
#define RR 32
#define CC 32
#define RC 1024
#define LL 2
#define CHUNK 32
#define NCHUNK 128
#define NEG_SLOPE 0.01f
#define LN_EPS 1e-5f

typedef __attribute__((ext_vector_type(8))) __bf16 bf16x8;
typedef __attribute__((ext_vector_type(4))) float f32x4;

__device__ __forceinline__ unsigned short f2bf(float f) {
    unsigned int u = __builtin_bit_cast(unsigned int, f);
    u += 0x7fffu + ((u >> 16) & 1u);   // round-to-nearest-even
    return (unsigned short)(u >> 16);
}

// ---------------------------------------------------------------------------
// Fused setup: f32->bf16 for x, W0, W1, plus Wt/Wc pack into Wtc[L,64,512].
#define NX4  524288   // 4096*512/4
#define NW04 524288   // 2*512*2048/4
#define NW14 131072   // 2*512*512/4
#define NCV  (NX4 + NW04 + NW14)
#define NPK  16384    // 2*64*512/4
__global__ __launch_bounds__(256) void setup_kernel(const float4* __restrict__ x,
                                                    const float4* __restrict__ W0,
                                                    const float4* __restrict__ W1,
                                                    const float* __restrict__ Wt,
                                                    const float* __restrict__ Wc,
                                                    ushort4* __restrict__ xb,
                                                    ushort4* __restrict__ W0b,
                                                    ushort4* __restrict__ W1b,
                                                    ushort4* __restrict__ Wtc) {
    int i = blockIdx.x * 256 + threadIdx.x;
    float4 v;
    ushort4* dst;
    int j;
    if (i < NCV) {
        const float4* src;
        if (i < NX4) { src = x; dst = xb; j = i; }
        else if (i < NX4 + NW04) { src = W0; dst = W0b; j = i - NX4; }
        else { src = W1; dst = W1b; j = i - NX4 - NW04; }
        v = src[j];
    } else {
        int ii = i - NCV;
        if (ii >= NPK) return;
        int e = ii * 4;
        int l = e >> 15;
        int r = (e >> 9) & 63;
        int k = e & 511;
        v = (r < 32) ? *(const float4*)&Wt[((size_t)l * 32 + r) * 512 + k]
                     : *(const float4*)&Wc[((size_t)l * 32 + (r - 32)) * 512 + k];
        dst = Wtc; j = ii;
    }
    ushort4 o;
    o.x = f2bf(v.x); o.y = f2bf(v.y); o.z = f2bf(v.z); o.w = f2bf(v.w);
    dst[j] = o;
}

// ---------------------------------------------------------------------------
// proj + denom fused: tc[4096,64] = h @ [Wt;Wc]^T, then per-row
//   tcabs[t, r]    = |tr_r| / (1e-8 + sum|tr| * sum|ct|)   (r < 32)
//   tcabs[t, 32+c] = |ct_c|
// Tile 128(M)x64(N), BK=64, 4 waves. grid (1, 32).
__global__ __launch_bounds__(256) void proj_denom_kernel(const unsigned short* __restrict__ A,
                                                         const unsigned short* __restrict__ B,
                                                         float* __restrict__ tcabs) {
    __shared__ __align__(16) unsigned short As[128 * 64];
    __shared__ __align__(16) unsigned short Bs[64 * 64];
    __shared__ float sums[128][2];
    const int tid = threadIdx.x;
    const int w = tid >> 6, lane = tid & 63;
    const int bm = blockIdx.y * 128;
    const int wr = w >> 1, wc = w & 1;
    const int fr = lane & 15, hi = lane >> 4;
    const int K = 512;
    // staging maps: A 4 vecs/thread, B 2 vecs/thread
    const unsigned short* ga[4]; int wa[4];
    const unsigned short* gb[2]; int wb[2];
#pragma unroll
    for (int u = 0; u < 4; ++u) {
        int vid = u * 256 + tid;
        int row = vid >> 3, k8 = vid & 7;
        ga[u] = A + (size_t)(bm + row) * K + k8 * 8;
        wa[u] = row * 64 + ((k8 ^ (row & 7)) * 8);
    }
#pragma unroll
    for (int u = 0; u < 2; ++u) {
        int vid = u * 256 + tid;
        int row = vid >> 3, k8 = vid & 7;
        gb[u] = B + (size_t)row * K + k8 * 8;
        wb[u] = row * 64 + ((k8 ^ (row & 7)) * 8);
    }
    f32x4 acc[4][2] = {};
    uint4 pa[4], pb[2];
#pragma unroll
    for (int u = 0; u < 4; ++u) pa[u] = *(const uint4*)ga[u];
#pragma unroll
    for (int u = 0; u < 2; ++u) pb[u] = *(const uint4*)gb[u];
    for (int k0 = 0; k0 < K; k0 += 64) {
        __syncthreads();
#pragma unroll
        for (int u = 0; u < 4; ++u) *(uint4*)&As[wa[u]] = pa[u];
#pragma unroll
        for (int u = 0; u < 2; ++u) *(uint4*)&Bs[wb[u]] = pb[u];
        __syncthreads();
        if (k0 + 64 < K) {
#pragma unroll
            for (int u = 0; u < 4; ++u) pa[u] = *(const uint4*)(ga[u] + k0 + 64);
#pragma unroll
            for (int u = 0; u < 2; ++u) pb[u] = *(const uint4*)(gb[u] + k0 + 64);
        }
#pragma unroll
        for (int kk = 0; kk < 2; ++kk) {
            const int ks = kk * 4 + hi;
            bf16x8 af[4], bfv[2];
#pragma unroll
            for (int mi = 0; mi < 4; ++mi) {
                int row = wr * 64 + mi * 16 + fr;
                af[mi] = *(const bf16x8*)&As[row * 64 + ((ks ^ (row & 7)) * 8)];
            }
#pragma unroll
            for (int ni = 0; ni < 2; ++ni) {
                int row = wc * 32 + ni * 16 + fr;
                bfv[ni] = *(const bf16x8*)&Bs[row * 64 + ((ks ^ (row & 7)) * 8)];
            }
#pragma unroll
            for (int mi = 0; mi < 4; ++mi)
#pragma unroll
                for (int ni = 0; ni < 2; ++ni)
                    acc[mi][ni] = __builtin_amdgcn_mfma_f32_16x16x32_bf16(
                        af[mi], bfv[ni], acc[mi][ni], 0, 0, 0);
        }
    }
    // epilogue: per-row abs sums (this wave covers 32 cols of each of 64 rows)
#pragma unroll
    for (int mi = 0; mi < 4; ++mi)
#pragma unroll
        for (int q = 0; q < 4; ++q) {
            float v = fabsf(acc[mi][0][q]) + fabsf(acc[mi][1][q]);
            v += __shfl_xor(v, 1);
            v += __shfl_xor(v, 2);
            v += __shfl_xor(v, 4);
            v += __shfl_xor(v, 8);
            if (fr == 0) sums[wr * 64 + mi * 16 + hi * 4 + q][wc] = v;
        }
    __syncthreads();
#pragma unroll
    for (int mi = 0; mi < 4; ++mi)
#pragma unroll
        for (int q = 0; q < 4; ++q) {
            int rl = wr * 64 + mi * 16 + hi * 4 + q;
            float inv = 1.f / (1e-8f + sums[rl][0] * sums[rl][1]);
            float scale = (wc == 0) ? inv : 1.f;
#pragma unroll
            for (int ni = 0; ni < 2; ++ni) {
                int col = wc * 32 + ni * 16 + fr;
                tcabs[(size_t)(bm + rl) * 64 + col] = fabsf(acc[mi][ni][q]) * scale;
            }
        }
}

// ---------------------------------------------------------------------------
// Scan pass 1: per (chunk, r, c) affine transform (alpha, beta) with resets.
__global__ __launch_bounds__(256) void scan_pass1(const float* __restrict__ tcabs,
                                                  const int* __restrict__ start,
                                                  const float* __restrict__ a,
                                                  const float* __restrict__ b,
                                                  float4* __restrict__ ab4) {
    int tid = blockIdx.x * 256 + threadIdx.x;   // NCHUNK*RC = 131072
    int rc = tid & (RC - 1);
    int chunk = tid >> 10;
    int r = rc >> 5, c = rc & 31;
    float e = expf(-fabsf(a[r]));
    float gr = e * cosf(b[c]);
    float gi = e * sinf(b[c]);
    float alr = 1.f, ali = 0.f, ber = 0.f, bei = 0.f;
    int t0 = chunk * CHUNK;
    for (int j = 0; j < CHUNK; ++j) {
        int t = t0 + j;
        float pre = tcabs[t * 64 + r] * tcabs[t * 64 + 32 + c];
        if (start[t]) {
            alr = 0.f; ali = 0.f; ber = pre; bei = 0.f;
        } else {
            float nbr = pre + gr * ber - gi * bei;
            float nbi =       gr * bei + gi * ber;
            float nar = gr * alr - gi * ali;
            float nai = gr * ali + gi * alr;
            ber = nbr; bei = nbi; alr = nar; ali = nai;
        }
    }
    ab4[chunk * RC + rc] = make_float4(alr, ali, ber, bei);
}

// ---------------------------------------------------------------------------
// Scan pass 2 + in-block lookback: compute incoming state by composing
// ab4[0..chunk-1] (8-deep prefetch), then rescan chunk, emit scaled (bf16).
// grid 512: chunk = bx>>2, rc = (bx&3)*256 + tx.
__global__ __launch_bounds__(256) void scan_pass2f(const float* __restrict__ tcabs,
                                                   const float4* __restrict__ ab4,
                                                   const int* __restrict__ start,
                                                   const float* __restrict__ a,
                                                   const float* __restrict__ b,
                                                   const float* __restrict__ s0r,
                                                   const float* __restrict__ s0i,
                                                   unsigned short* __restrict__ scaled) {
    int bx = blockIdx.x;
    int chunk = bx >> 2;
    int rc = (bx & 3) * 256 + threadIdx.x;
    int r = rc >> 5, c = rc & 31;
    float e = expf(-fabsf(a[r]));
    float gr = e * cosf(b[c]);
    float gi = e * sinf(b[c]);
    float sr = s0r[rc], si = s0i[rc];
    // lookback over prior chunk transforms
    int j = 0;
    for (; j + 8 <= chunk; j += 8) {
        float4 buf[8];
#pragma unroll
        for (int u = 0; u < 8; ++u) buf[u] = ab4[(j + u) * RC + rc];
#pragma unroll
        for (int u = 0; u < 8; ++u) {
            float nsr = buf[u].z + buf[u].x * sr - buf[u].y * si;
            float nsi = buf[u].w + buf[u].x * si + buf[u].y * sr;
            sr = nsr; si = nsi;
        }
    }
    for (; j < chunk; ++j) {
        float4 ab = ab4[j * RC + rc];
        float nsr = ab.z + ab.x * sr - ab.y * si;
        float nsi = ab.w + ab.x * si + ab.y * sr;
        sr = nsr; si = nsi;
    }
    // rescan own chunk, emit features
    int t0 = chunk * CHUNK;
    for (int jj = 0; jj < CHUNK; ++jj) {
        int t = t0 + jj;
        float pre = tcabs[t * 64 + r] * tcabs[t * 64 + 32 + c];
        if (start[t]) {
            sr = pre; si = 0.f;
        } else {
            float nsr = pre + gr * sr - gi * si;
            float nsi =       gr * si + gi * sr;
            sr = nsr; si = nsi;
        }
        float m = sqrtf(sr * sr + si * si);
        float mag = log1pf(m);
        float f = (m > 0.f) ? (mag / m) : 0.f;
        scaled[(size_t)t * 2048 + rc]        = f2bf(si * f);
        scaled[(size_t)t * 2048 + 1024 + rc] = f2bf(sr * f);
    }
}

// ---------------------------------------------------------------------------
// Cm_partial[z][4096,N] = A[4096,Kz]bf16 @ B[N,Kz]bf16^T  (split-K partials)
// Tile 128x64, BK=64, 4 waves. XOR slot swizzle (slot ^= row&7) write+read.
template <int K, int N, int SPLITK>
__global__ __launch_bounds__(256) void gemm_bt_mfma(const unsigned short* __restrict__ A,
                                                    const unsigned short* __restrict__ B,
                                                    float* __restrict__ Cm) {
    __shared__ __align__(16) unsigned short As[128 * 64];
    __shared__ __align__(16) unsigned short Bs[64 * 64];
    const int tid = threadIdx.x;
    const int w = tid >> 6, lane = tid & 63;
    const int bm = blockIdx.y * 128, bn = blockIdx.x * 64;
    const int kbeg = blockIdx.z * (K / SPLITK);
    const int kend = kbeg + (K / SPLITK);
    const int wr = w >> 1, wc = w & 1;
    const int fr = lane & 15, hi = lane >> 4;
    const unsigned short* ga[4]; int wa[4];
    const unsigned short* gb[2]; int wb[2];
#pragma unroll
    for (int u = 0; u < 4; ++u) {
        int vid = u * 256 + tid;
        int row = vid >> 3, k8 = vid & 7;
        ga[u] = A + (size_t)(bm + row) * K + k8 * 8;
        wa[u] = row * 64 + ((k8 ^ (row & 7)) * 8);
    }
#pragma unroll
    for (int u = 0; u < 2; ++u) {
        int vid = u * 256 + tid;
        int row = vid >> 3, k8 = vid & 7;
        gb[u] = B + (size_t)(bn + row) * K + k8 * 8;
        wb[u] = row * 64 + ((k8 ^ (row & 7)) * 8);
    }
    f32x4 acc[4][2] = {};
    uint4 pa[4], pb[2];
#pragma unroll
    for (int u = 0; u < 4; ++u) pa[u] = *(const uint4*)(ga[u] + kbeg);
#pragma unroll
    for (int u = 0; u < 2; ++u) pb[u] = *(const uint4*)(gb[u] + kbeg);
    for (int k0 = kbeg; k0 < kend; k0 += 64) {
        __syncthreads();
#pragma unroll
        for (int u = 0; u < 4; ++u) *(uint4*)&As[wa[u]] = pa[u];
#pragma unroll
        for (int u = 0; u < 2; ++u) *(uint4*)&Bs[wb[u]] = pb[u];
        __syncthreads();
        if (k0 + 64 < kend) {
#pragma unroll
            for (int u = 0; u < 4; ++u) pa[u] = *(const uint4*)(ga[u] + k0 + 64);
#pragma unroll
            for (int u = 0; u < 2; ++u) pb[u] = *(const uint4*)(gb[u] + k0 + 64);
        }
#pragma unroll
        for (int kk = 0; kk < 2; ++kk) {
            const int ks = kk * 4 + hi;
            bf16x8 af[4], bfv[2];
#pragma unroll
            for (int mi = 0; mi < 4; ++mi) {
                int row = wr * 64 + mi * 16 + fr;
                af[mi] = *(const bf16x8*)&As[row * 64 + ((ks ^ (row & 7)) * 8)];
            }
#pragma unroll
            for (int ni = 0; ni < 2; ++ni) {
                int row = wc * 32 + ni * 16 + fr;
                bfv[ni] = *(const bf16x8*)&Bs[row * 64 + ((ks ^ (row & 7)) * 8)];
            }
#pragma unroll
            for (int mi = 0; mi < 4; ++mi)
#pragma unroll
                for (int ni = 0; ni < 2; ++ni)
                    acc[mi][ni] = __builtin_amdgcn_mfma_f32_16x16x32_bf16(
                        af[mi], bfv[ni], acc[mi][ni], 0, 0, 0);
        }
    }
    // epilogue: C/D layout col=lane&15, row=(lane>>4)*4+reg  [m89]
    float* Cz = Cm + (size_t)blockIdx.z * TT * N;
    const int ccol0 = bn + wc * 32 + fr;
    const int crow0 = bm + wr * 64 + hi * 4;
#pragma unroll
    for (int ni = 0; ni < 2; ++ni) {
        int col = ccol0 + ni * 16;
#pragma unroll
        for (int mi = 0; mi < 4; ++mi)
#pragma unroll
            for (int q = 0; q < 4; ++q)
                Cz[(size_t)(crow0 + mi * 16 + q) * N + col] = acc[mi][ni][q];
    }
}

// ---------------------------------------------------------------------------
// Per-row: y = y0 + y1 + bias; LayerNorm + LeakyReLU.
__global__ __launch_bounds__(256) void ln_lrelu_kernel(const float* __restrict__ y0,
                                                       const float* __restrict__ y1,
                                                       const float* __restrict__ badd,
                                                       const float* __restrict__ g,
                                                       const float* __restrict__ be,
                                                       unsigned short* __restrict__ zb,
                                                       const float* __restrict__ res,
                                                       unsigned short* __restrict__ hbf,
                                                       float* __restrict__ fout) {
    int t = blockIdx.x;
    int tid = threadIdx.x;
    size_t base = (size_t)t * 512;
    float v0 = y0[base + tid] + y1[base + tid] + badd[tid];
    float v1 = y0[base + 256 + tid] + y1[base + 256 + tid] + badd[256 + tid];
    float s = v0 + v1, ss = v0 * v0 + v1 * v1;
#pragma unroll
    for (int o = 32; o > 0; o >>= 1) {
        s  += __shfl_down(s, o);
        ss += __shfl_down(ss, o);
    }
    __shared__ float sh[8];
    __shared__ float mrs[2];
    int wid = tid >> 6, lane = tid & 63;
    if (lane == 0) { sh[wid] = s; sh[4 + wid] = ss; }
    __syncthreads();
    if (tid == 0) {
        float S = sh[0] + sh[1] + sh[2] + sh[3];
        float SS = sh[4] + sh[5] + sh[6] + sh[7];
        float m = S * (1.f / 512.f);
        float var = SS * (1.f / 512.f) - m * m;
        mrs[0] = m;
        mrs[1] = rsqrtf(var + LN_EPS);
    }
    __syncthreads();
    float m = mrs[0], rs = mrs[1];
    float z0 = g[tid] * (v0 - m) * rs + be[tid];
    float z1 = g[256 + tid] * (v1 - m) * rs + be[256 + tid];
    z0 = (z0 > 0.f) ? z0 : NEG_SLOPE * z0;
    z1 = (z1 > 0.f) ? z1 : NEG_SLOPE * z1;
    if (zb)   { zb[base + tid] = f2bf(z0); zb[base + 256 + tid] = f2bf(z1); }
    if (hbf) {
        float h0 = (res ? res[base + tid] : 0.f) + z0;
        float h1 = (res ? res[base + 256 + tid] : 0.f) + z1;
        hbf[base + tid] = f2bf(h0);
        hbf[base + 256 + tid] = f2bf(h1);
    }
    if (fout) { fout[base + tid] = z0; fout[base + 256 + tid] = z1; }
}

// ---------------------------------------------------------------------------
extern "C" void kernel_launch(void* const* d_in, const int* in_sizes, int n_in,
                              void* d_out, int out_size, void* d_ws, size_t ws_size,
                              hipStream_t stream) {
    const float* x     = (const float*)d_in[0];
    const int*   start = (const int*)d_in[1];
    const float* s0r = (const float*)d_in[3];
    const float* s0i = (const float*)d_in[4];
    const float* Wt  = (const float*)d_in[5];
    const float* Wc  = (const float*)d_in[6];
    const float* a   = (const float*)d_in[7];
    const float* b   = (const float*)d_in[8];
    const float* W0  = (const float*)d_in[9];
    const float* b0  = (const float*)d_in[10];
    const float* g0  = (const float*)d_in[11];
    const float* be0 = (const float*)d_in[12];
    const float* W1  = (const float*)d_in[13];
    const float* b1  = (const float*)d_in[14];
    const float* g1  = (const float*)d_in[15];
    const float* be1 = (const float*)d_in[16];
    float* out = (float*)d_out;
    float* ws  = (float*)d_ws;

    // workspace layout (float-unit offsets, all 16B aligned)  ~50 MB
    float* p = ws;
    float* tcabs  = p; p += 262144;                  // [4096][64] f32 (invd folded)
    float4* ab4   = (float4*)p; p += 524288;         // [128][1024] float4
    unsigned short* scaled = (unsigned short*)p; p += 4194304;   // [4096][2048] bf16
    float* ybufp  = p; p += 4194304;                 // [2][4096][512] f32 partials
    unsigned short* zbuf_bf = (unsigned short*)p; p += 1048576;  // [4096][512] bf16
    unsigned short* x_bf    = (unsigned short*)p; p += 1048576;
    unsigned short* h_bf    = (unsigned short*)p; p += 1048576;
    unsigned short* Wtcbf   = (unsigned short*)p; p += 32768;    // [2][64][512] bf16
    unsigned short* W0bf    = (unsigned short*)p; p += 1048576;  // [2][512][2048] bf16
    unsigned short* W1bf    = (unsigned short*)p; p += 262144;   // [2][512][512] bf16

    setup_kernel<<<(NCV + NPK + 255) / 256, 256, 0, stream>>>(
        (const float4*)x, (const float4*)W0, (const float4*)W1, Wt, Wc,
        (ushort4*)x_bf, (ushort4*)W0bf, (ushort4*)W1bf, (ushort4*)Wtcbf);

    for (int i = 0; i < LL; ++i) {
        const unsigned short* hb = (i == 0) ? x_bf : h_bf;
        proj_denom_kernel<<<dim3(1, 32), 256, 0, stream>>>(
            hb, Wtcbf + (size_t)i * 64 * 512, tcabs);
        scan_pass1<<<NCHUNK * RC / 256, 256, 0, stream>>>(
            tcabs, start, a + i * RR, b + i * CC, ab4);
        scan_pass2f<<<NCHUNK * 4, 256, 0, stream>>>(
            tcabs, ab4, start, a + i * RR, b + i * CC,
            s0r + i * RC, s0i + i * RC, scaled);
        gemm_bt_mfma<2048, 512, 2><<<dim3(8, 32, 2), 256, 0, stream>>>(
            scaled, W0bf + (size_t)i * 512 * 2048, ybufp);
        ln_lrelu_kernel<<<TT, 256, 0, stream>>>(
            ybufp, ybufp + (size_t)TT * 512, b0 + i * DD, g0 + i * DD, be0 + i * DD,
            zbuf_bf, nullptr, nullptr, nullptr);
        gemm_bt_mfma<512, 512, 2><<<dim3(8, 32, 2), 256, 0, stream>>>(
            zbuf_bf, W1bf + (size_t)i * 512 * 512, ybufp);
        ln_lrelu_kernel<<<TT, 256, 0, stream>>>(
            ybufp, ybufp + (size_t)TT * 512, b1 + i * DD, g1 + i * DD, be1 + i * DD,
            nullptr,
            (i < LL - 1) ? x : nullptr,
            (i < LL - 1) ? h_bf : nullptr,
            (i == LL - 1) ? out : nullptr);
    }
}

// Round 6
// 208.936 us; speedup vs baseline: 1.5548x; 1.5548x over previous
//
#include <hip/hip_runtime.h>
#include <math.h>

// Problem constants
#define TT 4096
#define DD 512
#define RR 32
#define CC 32
#define RC 1024
#define LL 2
#define CHUNK 32
#define NCHUNK 128
#define NEG_SLOPE 0.01f
#define LN_EPS 1e-5f

typedef __attribute__((ext_vector_type(8))) __bf16 bf16x8;
typedef __attribute__((ext_vector_type(4))) float f32x4;

__device__ __forceinline__ unsigned short f2bf(float f) {
    unsigned int u = __builtin_bit_cast(unsigned int, f);
    u += 0x7fffu + ((u >> 16) & 1u);   // round-to-nearest-even
    return (unsigned short)(u >> 16);
}

// ---------------------------------------------------------------------------
// Fused setup: f32->bf16 for x, W0, W1, plus Wt/Wc pack into Wtc[L,64,512].
#define NX4  524288   // 4096*512/4
#define NW04 524288   // 2*512*2048/4
#define NW14 131072   // 2*512*512/4
#define NCV  (NX4 + NW04 + NW14)
#define NPK  16384    // 2*64*512/4
__global__ __launch_bounds__(256) void setup_kernel(const float4* __restrict__ x,
                                                    const float4* __restrict__ W0,
                                                    const float4* __restrict__ W1,
                                                    const float* __restrict__ Wt,
                                                    const float* __restrict__ Wc,
                                                    ushort4* __restrict__ xb,
                                                    ushort4* __restrict__ W0b,
                                                    ushort4* __restrict__ W1b,
                                                    ushort4* __restrict__ Wtc) {
    int i = blockIdx.x * 256 + threadIdx.x;
    float4 v;
    ushort4* dst;
    int j;
    if (i < NCV) {
        const float4* src;
        if (i < NX4) { src = x; dst = xb; j = i; }
        else if (i < NX4 + NW04) { src = W0; dst = W0b; j = i - NX4; }
        else { src = W1; dst = W1b; j = i - NX4 - NW04; }
        v = src[j];
    } else {
        int ii = i - NCV;
        if (ii >= NPK) return;
        int e = ii * 4;
        int l = e >> 15;
        int r = (e >> 9) & 63;
        int k = e & 511;
        v = (r < 32) ? *(const float4*)&Wt[((size_t)l * 32 + r) * 512 + k]
                     : *(const float4*)&Wc[((size_t)l * 32 + (r - 32)) * 512 + k];
        dst = Wtc; j = ii;
    }
    ushort4 o;
    o.x = f2bf(v.x); o.y = f2bf(v.y); o.z = f2bf(v.z); o.w = f2bf(v.w);
    dst[j] = o;
}

// ---------------------------------------------------------------------------
// proj + denom fused: tc[4096,64] = h @ [Wt;Wc]^T, then per-row
//   tcabs[t, r]    = |tr_r| / (1e-8 + sum|tr| * sum|ct|)   (r < 32)
//   tcabs[t, 32+c] = |ct_c|
// Tile 128(M)x64(N), BK=32, 4 waves, named-scalar staging (NO arrays). grid (1,32).
__global__ __launch_bounds__(256) void proj_denom_kernel(const unsigned short* __restrict__ A,
                                                         const unsigned short* __restrict__ B,
                                                         float* __restrict__ tcabs) {
    __shared__ __align__(16) unsigned short As[128 * 32];
    __shared__ __align__(16) unsigned short Bs[64 * 32];
    __shared__ float sums[128][2];
    const int tid = threadIdx.x;
    const int w = tid >> 6, lane = tid & 63;
    const int bm = blockIdx.y * 128;
    const int wr = w >> 1, wc = w & 1;
    const int lr = lane >> 2;
    const int sl = lane & 3;
    const int swz_st = sl ^ ((lr >> 1) & 3);
    const int K = 512;
    const unsigned short* gA0 = A + (size_t)(bm + w * 16 + lr) * K + sl * 8;
    const unsigned short* gA1 = A + (size_t)(bm + 64 + w * 16 + lr) * K + sl * 8;
    const unsigned short* gB  = B + (size_t)(w * 16 + lr) * K + sl * 8;
    const int wA0 = (w * 16 + lr) * 32 + swz_st * 8;
    const int wA1 = (64 + w * 16 + lr) * 32 + swz_st * 8;
    const int wB  = (w * 16 + lr) * 32 + swz_st * 8;
    const int fr = lane & 15, hi = lane >> 4;
    const int kslot = hi ^ ((fr >> 1) & 3);
    f32x4 acc[4][2] = {};

    uint4 va0 = *(const uint4*)gA0;
    uint4 va1 = *(const uint4*)gA1;
    uint4 vb  = *(const uint4*)gB;
    for (int k0 = 0; k0 < K; k0 += 32) {
        __syncthreads();
        *(uint4*)&As[wA0] = va0;
        *(uint4*)&As[wA1] = va1;
        *(uint4*)&Bs[wB]  = vb;
        __syncthreads();
        if (k0 + 32 < K) {
            va0 = *(const uint4*)(gA0 + k0 + 32);
            va1 = *(const uint4*)(gA1 + k0 + 32);
            vb  = *(const uint4*)(gB  + k0 + 32);
        }
        bf16x8 af[4], bfv[2];
#pragma unroll
        for (int mi = 0; mi < 4; ++mi) {
            int row = wr * 64 + mi * 16 + fr;
            af[mi] = *(const bf16x8*)&As[row * 32 + kslot * 8];
        }
#pragma unroll
        for (int ni = 0; ni < 2; ++ni) {
            int row = wc * 32 + ni * 16 + fr;
            bfv[ni] = *(const bf16x8*)&Bs[row * 32 + kslot * 8];
        }
#pragma unroll
        for (int mi = 0; mi < 4; ++mi)
#pragma unroll
            for (int ni = 0; ni < 2; ++ni)
                acc[mi][ni] = __builtin_amdgcn_mfma_f32_16x16x32_bf16(
                    af[mi], bfv[ni], acc[mi][ni], 0, 0, 0);
    }
    // epilogue: per-row abs sums (this wave covers 32 cols of each of 64 rows)
#pragma unroll
    for (int mi = 0; mi < 4; ++mi)
#pragma unroll
        for (int q = 0; q < 4; ++q) {
            float v = fabsf(acc[mi][0][q]) + fabsf(acc[mi][1][q]);
            v += __shfl_xor(v, 1);
            v += __shfl_xor(v, 2);
            v += __shfl_xor(v, 4);
            v += __shfl_xor(v, 8);
            if (fr == 0) sums[wr * 64 + mi * 16 + hi * 4 + q][wc] = v;
        }
    __syncthreads();
#pragma unroll
    for (int mi = 0; mi < 4; ++mi)
#pragma unroll
        for (int q = 0; q < 4; ++q) {
            int rl = wr * 64 + mi * 16 + hi * 4 + q;
            float inv = 1.f / (1e-8f + sums[rl][0] * sums[rl][1]);
            float scale = (wc == 0) ? inv : 1.f;
#pragma unroll
            for (int ni = 0; ni < 2; ++ni) {
                int col = wc * 32 + ni * 16 + fr;
                tcabs[(size_t)(bm + rl) * 64 + col] = fabsf(acc[mi][ni][q]) * scale;
            }
        }
}

// ---------------------------------------------------------------------------
// Scan pass 1: per (chunk, r, c) affine transform (alpha, beta) with resets.
__global__ __launch_bounds__(256) void scan_pass1(const float* __restrict__ tcabs,
                                                  const int* __restrict__ start,
                                                  const float* __restrict__ a,
                                                  const float* __restrict__ b,
                                                  float4* __restrict__ ab4) {
    int tid = blockIdx.x * 256 + threadIdx.x;   // NCHUNK*RC = 131072
    int rc = tid & (RC - 1);
    int chunk = tid >> 10;
    int r = rc >> 5, c = rc & 31;
    float e = expf(-fabsf(a[r]));
    float gr = e * cosf(b[c]);
    float gi = e * sinf(b[c]);
    float alr = 1.f, ali = 0.f, ber = 0.f, bei = 0.f;
    int t0 = chunk * CHUNK;
    for (int j = 0; j < CHUNK; ++j) {
        int t = t0 + j;
        float pre = tcabs[t * 64 + r] * tcabs[t * 64 + 32 + c];
        if (start[t]) {
            alr = 0.f; ali = 0.f; ber = pre; bei = 0.f;
        } else {
            float nbr = pre + gr * ber - gi * bei;
            float nbi =       gr * bei + gi * ber;
            float nar = gr * alr - gi * ali;
            float nai = gr * ali + gi * alr;
            ber = nbr; bei = nbi; alr = nar; ali = nai;
        }
    }
    ab4[chunk * RC + rc] = make_float4(alr, ali, ber, bei);
}

// ---------------------------------------------------------------------------
// Scan pass 2 + in-block lookback: compose ab4[0..chunk-1] (8-deep prefetch),
// then rescan own chunk, emit scaled features (bf16).
// grid 512: chunk = bx>>2, rc = (bx&3)*256 + tx.
__global__ __launch_bounds__(256) void scan_pass2f(const float* __restrict__ tcabs,
                                                   const float4* __restrict__ ab4,
                                                   const int* __restrict__ start,
                                                   const float* __restrict__ a,
                                                   const float* __restrict__ b,
                                                   const float* __restrict__ s0r,
                                                   const float* __restrict__ s0i,
                                                   unsigned short* __restrict__ scaled) {
    int bx = blockIdx.x;
    int chunk = bx >> 2;
    int rc = (bx & 3) * 256 + threadIdx.x;
    int r = rc >> 5, c = rc & 31;
    float e = expf(-fabsf(a[r]));
    float gr = e * cosf(b[c]);
    float gi = e * sinf(b[c]);
    float sr = s0r[rc], si = s0i[rc];
    // lookback over prior chunk transforms
    int j = 0;
    for (; j + 8 <= chunk; j += 8) {
        float4 buf[8];
#pragma unroll
        for (int u = 0; u < 8; ++u) buf[u] = ab4[(j + u) * RC + rc];
#pragma unroll
        for (int u = 0; u < 8; ++u) {
            float nsr = buf[u].z + buf[u].x * sr - buf[u].y * si;
            float nsi = buf[u].w + buf[u].x * si + buf[u].y * sr;
            sr = nsr; si = nsi;
        }
    }
    for (; j < chunk; ++j) {
        float4 ab = ab4[j * RC + rc];
        float nsr = ab.z + ab.x * sr - ab.y * si;
        float nsi = ab.w + ab.x * si + ab.y * sr;
        sr = nsr; si = nsi;
    }
    // rescan own chunk, emit features
    int t0 = chunk * CHUNK;
    for (int jj = 0; jj < CHUNK; ++jj) {
        int t = t0 + jj;
        float pre = tcabs[t * 64 + r] * tcabs[t * 64 + 32 + c];
        if (start[t]) {
            sr = pre; si = 0.f;
        } else {
            float nsr = pre + gr * sr - gi * si;
            float nsi =       gr * si + gi * sr;
            sr = nsr; si = nsi;
        }
        float m = sqrtf(sr * sr + si * si);
        float mag = log1pf(m);
        float f = (m > 0.f) ? (mag / m) : 0.f;
        scaled[(size_t)t * 2048 + rc]        = f2bf(si * f);
        scaled[(size_t)t * 2048 + 1024 + rc] = f2bf(sr * f);
    }
}

// ---------------------------------------------------------------------------
// Cm_partial[z][4096,N] = A[4096,Kz]bf16 @ B[N,Kz]bf16^T  (split-K partials)
// Tile 128x64, BK=32, 4 waves, named-scalar staging (round-4 proven version).
template <int K, int N, int SPLITK>
__global__ __launch_bounds__(256) void gemm_bt_mfma(const unsigned short* __restrict__ A,
                                                    const unsigned short* __restrict__ B,
                                                    float* __restrict__ Cm) {
    __shared__ __align__(16) unsigned short As[128 * 32];
    __shared__ __align__(16) unsigned short Bs[64 * 32];
    const int tid = threadIdx.x;
    const int w = tid >> 6, lane = tid & 63;
    const int bm = blockIdx.y * 128, bn = blockIdx.x * 64;
    const int kbeg = blockIdx.z * (K / SPLITK);
    const int kend = kbeg + (K / SPLITK);
    const int wr = w >> 1, wc = w & 1;
    const int lr = lane >> 2;
    const int sl = lane & 3;
    const int swz_st = sl ^ ((lr >> 1) & 3);
    const size_t a_row0 = (size_t)(bm + w * 16 + lr);
    const size_t a_row1 = (size_t)(bm + 64 + w * 16 + lr);
    const size_t b_row  = (size_t)(bn + w * 16 + lr);
    const unsigned short* gA0 = A + a_row0 * K + sl * 8;
    const unsigned short* gA1 = A + a_row1 * K + sl * 8;
    const unsigned short* gB  = B + b_row  * K + sl * 8;
    const int wA0 = (w * 16 + lr) * 32 + swz_st * 8;
    const int wA1 = (64 + w * 16 + lr) * 32 + swz_st * 8;
    const int wB  = (w * 16 + lr) * 32 + swz_st * 8;
    const int fr = lane & 15, hi = lane >> 4;
    const int kslot = hi ^ ((fr >> 1) & 3);
    f32x4 acc[4][2] = {};

    uint4 va0 = *(const uint4*)(gA0 + kbeg);
    uint4 va1 = *(const uint4*)(gA1 + kbeg);
    uint4 vb  = *(const uint4*)(gB  + kbeg);
    for (int k0 = kbeg; k0 < kend; k0 += 32) {
        __syncthreads();
        *(uint4*)&As[wA0] = va0;
        *(uint4*)&As[wA1] = va1;
        *(uint4*)&Bs[wB]  = vb;
        __syncthreads();
        if (k0 + 32 < kend) {
            va0 = *(const uint4*)(gA0 + k0 + 32);
            va1 = *(const uint4*)(gA1 + k0 + 32);
            vb  = *(const uint4*)(gB  + k0 + 32);
        }
        bf16x8 af[4], bfv[2];
#pragma unroll
        for (int mi = 0; mi < 4; ++mi) {
            int row = wr * 64 + mi * 16 + fr;
            af[mi] = *(const bf16x8*)&As[row * 32 + kslot * 8];
        }
#pragma unroll
        for (int ni = 0; ni < 2; ++ni) {
            int row = wc * 32 + ni * 16 + fr;
            bfv[ni] = *(const bf16x8*)&Bs[row * 32 + kslot * 8];
        }
#pragma unroll
        for (int mi = 0; mi < 4; ++mi)
#pragma unroll
            for (int ni = 0; ni < 2; ++ni)
                acc[mi][ni] = __builtin_amdgcn_mfma_f32_16x16x32_bf16(
                    af[mi], bfv[ni], acc[mi][ni], 0, 0, 0);
    }
    // epilogue: C/D layout col=lane&15, row=(lane>>4)*4+reg  [m89]
    float* Cz = Cm + (size_t)blockIdx.z * TT * N;
    const int ccol0 = bn + wc * 32 + fr;
    const int crow0 = bm + wr * 64 + hi * 4;
#pragma unroll
    for (int ni = 0; ni < 2; ++ni) {
        int col = ccol0 + ni * 16;
#pragma unroll
        for (int mi = 0; mi < 4; ++mi)
#pragma unroll
            for (int q = 0; q < 4; ++q)
                Cz[(size_t)(crow0 + mi * 16 + q) * N + col] = acc[mi][ni][q];
    }
}

// ---------------------------------------------------------------------------
// Per-row: y = y0 + y1 + bias; LayerNorm + LeakyReLU.
__global__ __launch_bounds__(256) void ln_lrelu_kernel(const float* __restrict__ y0,
                                                       const float* __restrict__ y1,
                                                       const float* __restrict__ badd,
                                                       const float* __restrict__ g,
                                                       const float* __restrict__ be,
                                                       unsigned short* __restrict__ zb,
                                                       const float* __restrict__ res,
                                                       unsigned short* __restrict__ hbf,
                                                       float* __restrict__ fout) {
    int t = blockIdx.x;
    int tid = threadIdx.x;
    size_t base = (size_t)t * 512;
    float v0 = y0[base + tid] + y1[base + tid] + badd[tid];
    float v1 = y0[base + 256 + tid] + y1[base + 256 + tid] + badd[256 + tid];
    float s = v0 + v1, ss = v0 * v0 + v1 * v1;
#pragma unroll
    for (int o = 32; o > 0; o >>= 1) {
        s  += __shfl_down(s, o);
        ss += __shfl_down(ss, o);
    }
    __shared__ float sh[8];
    __shared__ float mrs[2];
    int wid = tid >> 6, lane = tid & 63;
    if (lane == 0) { sh[wid] = s; sh[4 + wid] = ss; }
    __syncthreads();
    if (tid == 0) {
        float S = sh[0] + sh[1] + sh[2] + sh[3];
        float SS = sh[4] + sh[5] + sh[6] + sh[7];
        float m = S * (1.f / 512.f);
        float var = SS * (1.f / 512.f) - m * m;
        mrs[0] = m;
        mrs[1] = rsqrtf(var + LN_EPS);
    }
    __syncthreads();
    float m = mrs[0], rs = mrs[1];
    float z0 = g[tid] * (v0 - m) * rs + be[tid];
    float z1 = g[256 + tid] * (v1 - m) * rs + be[256 + tid];
    z0 = (z0 > 0.f) ? z0 : NEG_SLOPE * z0;
    z1 = (z1 > 0.f) ? z1 : NEG_SLOPE * z1;
    if (zb)   { zb[base + tid] = f2bf(z0); zb[base + 256 + tid] = f2bf(z1); }
    if (hbf) {
        float h0 = (res ? res[base + tid] : 0.f) + z0;
        float h1 = (res ? res[base + 256 + tid] : 0.f) + z1;
        hbf[base + tid] = f2bf(h0);
        hbf[base + 256 + tid] = f2bf(h1);
    }
    if (fout) { fout[base + tid] = z0; fout[base + 256 + tid] = z1; }
}

// ---------------------------------------------------------------------------
extern "C" void kernel_launch(void* const* d_in, const int* in_sizes, int n_in,
                              void* d_out, int out_size, void* d_ws, size_t ws_size,
                              hipStream_t stream) {
    const float* x     = (const float*)d_in[0];
    const int*   start = (const int*)d_in[1];
    const float* s0r = (const float*)d_in[3];
    const float* s0i = (const float*)d_in[4];
    const float* Wt  = (const float*)d_in[5];
    const float* Wc  = (const float*)d_in[6];
    const float* a   = (const float*)d_in[7];
    const float* b   = (const float*)d_in[8];
    const float* W0  = (const float*)d_in[9];
    const float* b0  = (const float*)d_in[10];
    const float* g0  = (const float*)d_in[11];
    const float* be0 = (const float*)d_in[12];
    const float* W1  = (const float*)d_in[13];
    const float* b1  = (const float*)d_in[14];
    const float* g1  = (const float*)d_in[15];
    const float* be1 = (const float*)d_in[16];
    float* out = (float*)d_out;
    float* ws  = (float*)d_ws;

    // workspace layout (float-unit offsets, all 16B aligned)  ~50 MB
    float* p = ws;
    float* tcabs  = p; p += 262144;                  // [4096][64] f32 (invd folded)
    float4* ab4   = (float4*)p; p += 524288;         // [128][1024] float4
    unsigned short* scaled = (unsigned short*)p; p += 4194304;   // [4096][2048] bf16
    float* ybufp  = p; p += 4194304;                 // [2][4096][512] f32 partials
    unsigned short* zbuf_bf = (unsigned short*)p; p += 1048576;  // [4096][512] bf16
    unsigned short* x_bf    = (unsigned short*)p; p += 1048576;
    unsigned short* h_bf    = (unsigned short*)p; p += 1048576;
    unsigned short* Wtcbf   = (unsigned short*)p; p += 32768;    // [2][64][512] bf16
    unsigned short* W0bf    = (unsigned short*)p; p += 1048576;  // [2][512][2048] bf16
    unsigned short* W1bf    = (unsigned short*)p; p += 262144;   // [2][512][512] bf16

    setup_kernel<<<(NCV + NPK + 255) / 256, 256, 0, stream>>>(
        (const float4*)x, (const float4*)W0, (const float4*)W1, Wt, Wc,
        (ushort4*)x_bf, (ushort4*)W0bf, (ushort4*)W1bf, (ushort4*)Wtcbf);

    for (int i = 0; i < LL; ++i) {
        const unsigned short* hb = (i == 0) ? x_bf : h_bf;
        proj_denom_kernel<<<dim3(1, 32), 256, 0, stream>>>(
            hb, Wtcbf + (size_t)i * 64 * 512, tcabs);
        scan_pass1<<<NCHUNK * RC / 256, 256, 0, stream>>>(
            tcabs, start, a + i * RR, b + i * CC, ab4);
        scan_pass2f<<<NCHUNK * 4, 256, 0, stream>>>(
            tcabs, ab4, start, a + i * RR, b + i * CC,
            s0r + i * RC, s0i + i * RC, scaled);
        gemm_bt_mfma<2048, 512, 2><<<dim3(8, 32, 2), 256, 0, stream>>>(
            scaled, W0bf + (size_t)i * 512 * 2048, ybufp);
        ln_lrelu_kernel<<<TT, 256, 0, stream>>>(
            ybufp, ybufp + (size_t)TT * 512, b0 + i * DD, g0 + i * DD, be0 + i * DD,
            zbuf_bf, nullptr, nullptr, nullptr);
        gemm_bt_mfma<512, 512, 2><<<dim3(8, 32, 2), 256, 0, stream>>>(
            zbuf_bf, W1bf + (size_t)i * 512 * 512, ybufp);
        ln_lrelu_kernel<<<TT, 256, 0, stream>>>(
            ybufp, ybufp + (size_t)TT * 512, b1 + i * DD, g1 + i * DD, be1 + i * DD,
            nullptr,
            (i < LL - 1) ? x : nullptr,
            (i < LL - 1) ? h_bf : nullptr,
            (i == LL - 1) ? out : nullptr);
    }
}

// Round 7
// 202.362 us; speedup vs baseline: 1.6053x; 1.0325x over previous
//
#include <hip/hip_runtime.h>
#include <math.h>

// Problem constants
#define TT 4096
#define DD 512
#define RR 32
#define CC 32
#define RC 1024
#define LL 2
#define CHUNK 32
#define NCHUNK 128
#define NEG_SLOPE 0.01f
#define LN_EPS 1e-5f

typedef __attribute__((ext_vector_type(8))) __bf16 bf16x8;
typedef __attribute__((ext_vector_type(4))) float f32x4;

__device__ __forceinline__ unsigned short f2bf(float f) {
    unsigned int u = __builtin_bit_cast(unsigned int, f);
    u += 0x7fffu + ((u >> 16) & 1u);   // round-to-nearest-even
    return (unsigned short)(u >> 16);
}

// ---------------------------------------------------------------------------
// Fused setup: f32->bf16 for x, W0, W1, plus Wt/Wc pack into Wtc[L,64,512].
#define NX4  524288   // 4096*512/4
#define NW04 524288   // 2*512*2048/4
#define NW14 131072   // 2*512*512/4
#define NCV  (NX4 + NW04 + NW14)
#define NPK  16384    // 2*64*512/4
__global__ __launch_bounds__(256) void setup_kernel(const float4* __restrict__ x,
                                                    const float4* __restrict__ W0,
                                                    const float4* __restrict__ W1,
                                                    const float* __restrict__ Wt,
                                                    const float* __restrict__ Wc,
                                                    ushort4* __restrict__ xb,
                                                    ushort4* __restrict__ W0b,
                                                    ushort4* __restrict__ W1b,
                                                    ushort4* __restrict__ Wtc) {
    int i = blockIdx.x * 256 + threadIdx.x;
    float4 v;
    ushort4* dst;
    int j;
    if (i < NCV) {
        const float4* src;
        if (i < NX4) { src = x; dst = xb; j = i; }
        else if (i < NX4 + NW04) { src = W0; dst = W0b; j = i - NX4; }
        else { src = W1; dst = W1b; j = i - NX4 - NW04; }
        v = src[j];
    } else {
        int ii = i - NCV;
        if (ii >= NPK) return;
        int e = ii * 4;
        int l = e >> 15;
        int r = (e >> 9) & 63;
        int k = e & 511;
        v = (r < 32) ? *(const float4*)&Wt[((size_t)l * 32 + r) * 512 + k]
                     : *(const float4*)&Wc[((size_t)l * 32 + (r - 32)) * 512 + k];
        dst = Wtc; j = ii;
    }
    ushort4 o;
    o.x = f2bf(v.x); o.y = f2bf(v.y); o.z = f2bf(v.z); o.w = f2bf(v.w);
    dst[j] = o;
}

// ---------------------------------------------------------------------------
// proj + denom fused: tc[4096,64] = h @ [Wt;Wc]^T, then per-row
//   tcabs[t, r]    = |tr_r| / (1e-8 + sum|tr| * sum|ct|)   (r < 32)
//   tcabs[t, 32+c] = |ct_c|
// Tile 64(M)x64(N), BK=32, 4 waves; wave w owns rows w*16..w*16+15 (1x4 frags)
// -> denom epilogue is pure shfl_xor, no LDS. grid 64 blocks.
__global__ __launch_bounds__(256) void proj_denom_kernel(const unsigned short* __restrict__ A,
                                                         const unsigned short* __restrict__ B,
                                                         float* __restrict__ tcabs) {
    __shared__ __align__(16) unsigned short As[64 * 32];
    __shared__ __align__(16) unsigned short Bs[64 * 32];
    const int tid = threadIdx.x;
    const int w = tid >> 6, lane = tid & 63;
    const int bm = blockIdx.x * 64;
    const int K = 512;
    // staging: one A-vec + one B-vec per thread (named scalars, no arrays)
    const int srow = tid >> 2;           // 0..63
    const int sl = tid & 3;              // 16B slot
    const int sswz = (sl ^ ((srow >> 1) & 3)) * 8;
    const unsigned short* gA = A + (size_t)(bm + srow) * K + sl * 8;
    const unsigned short* gB = B + (size_t)srow * K + sl * 8;
    const int wA = srow * 32 + sswz;
    const int wB = srow * 32 + sswz;
    const int fr = lane & 15, hi = lane >> 4;
    const int kslot = hi ^ ((fr >> 1) & 3);
    f32x4 acc0 = {}, acc1 = {}, acc2 = {}, acc3 = {};

    uint4 va = *(const uint4*)gA;
    uint4 vb = *(const uint4*)gB;
    for (int k0 = 0; k0 < K; k0 += 32) {
        __syncthreads();
        *(uint4*)&As[wA] = va;
        *(uint4*)&Bs[wB] = vb;
        __syncthreads();
        if (k0 + 32 < K) {
            va = *(const uint4*)(gA + k0 + 32);
            vb = *(const uint4*)(gB + k0 + 32);
        }
        const int arow = w * 16 + fr;
        bf16x8 af = *(const bf16x8*)&As[arow * 32 + kslot * 8];
        bf16x8 b0 = *(const bf16x8*)&Bs[(0 * 16 + fr) * 32 + kslot * 8];
        bf16x8 b1 = *(const bf16x8*)&Bs[(1 * 16 + fr) * 32 + kslot * 8];
        bf16x8 b2 = *(const bf16x8*)&Bs[(2 * 16 + fr) * 32 + kslot * 8];
        bf16x8 b3 = *(const bf16x8*)&Bs[(3 * 16 + fr) * 32 + kslot * 8];
        acc0 = __builtin_amdgcn_mfma_f32_16x16x32_bf16(af, b0, acc0, 0, 0, 0);
        acc1 = __builtin_amdgcn_mfma_f32_16x16x32_bf16(af, b1, acc1, 0, 0, 0);
        acc2 = __builtin_amdgcn_mfma_f32_16x16x32_bf16(af, b2, acc2, 0, 0, 0);
        acc3 = __builtin_amdgcn_mfma_f32_16x16x32_bf16(af, b3, acc3, 0, 0, 0);
    }
    // epilogue: row = bm + w*16 + hi*4 + q, cols {fr, fr+16, fr+32, fr+48}.
    // cols 0..31 = tr (scaled by inv), 32..63 = ct.
#pragma unroll
    for (int q = 0; q < 4; ++q) {
        float a0 = fabsf(acc0[q]), a1 = fabsf(acc1[q]);
        float a2 = fabsf(acc2[q]), a3 = fabsf(acc3[q]);
        float st = a0 + a1, sc = a2 + a3;
        st += __shfl_xor(st, 1); sc += __shfl_xor(sc, 1);
        st += __shfl_xor(st, 2); sc += __shfl_xor(sc, 2);
        st += __shfl_xor(st, 4); sc += __shfl_xor(sc, 4);
        st += __shfl_xor(st, 8); sc += __shfl_xor(sc, 8);
        float inv = 1.f / (1e-8f + st * sc);
        size_t rb = (size_t)(bm + w * 16 + hi * 4 + q) * 64;
        tcabs[rb + fr]      = a0 * inv;
        tcabs[rb + fr + 16] = a1 * inv;
        tcabs[rb + fr + 32] = a2;
        tcabs[rb + fr + 48] = a3;
    }
}

// ---------------------------------------------------------------------------
// Scan pass 1: per (chunk, r, c) affine transform (alpha, beta) with resets.
__global__ __launch_bounds__(256) void scan_pass1(const float* __restrict__ tcabs,
                                                  const int* __restrict__ start,
                                                  const float* __restrict__ a,
                                                  const float* __restrict__ b,
                                                  float4* __restrict__ ab4) {
    int tid = blockIdx.x * 256 + threadIdx.x;   // NCHUNK*RC = 131072
    int rc = tid & (RC - 1);
    int chunk = tid >> 10;
    int r = rc >> 5, c = rc & 31;
    float e = expf(-fabsf(a[r]));
    float gr = e * cosf(b[c]);
    float gi = e * sinf(b[c]);
    float alr = 1.f, ali = 0.f, ber = 0.f, bei = 0.f;
    int t0 = chunk * CHUNK;
    for (int j = 0; j < CHUNK; ++j) {
        int t = t0 + j;
        float pre = tcabs[t * 64 + r] * tcabs[t * 64 + 32 + c];
        if (start[t]) {
            alr = 0.f; ali = 0.f; ber = pre; bei = 0.f;
        } else {
            float nbr = pre + gr * ber - gi * bei;
            float nbi =       gr * bei + gi * ber;
            float nar = gr * alr - gi * ali;
            float nai = gr * ali + gi * alr;
            ber = nbr; bei = nbi; alr = nar; ali = nai;
        }
    }
    ab4[chunk * RC + rc] = make_float4(alr, ali, ber, bei);
}

// ---------------------------------------------------------------------------
// Scan pass 2 + in-block lookback: compose ab4[0..chunk-1] (8-deep prefetch),
// then rescan own chunk, emit scaled features (bf16).
// grid 512: chunk = bx>>2, rc = (bx&3)*256 + tx.
__global__ __launch_bounds__(256) void scan_pass2f(const float* __restrict__ tcabs,
                                                   const float4* __restrict__ ab4,
                                                   const int* __restrict__ start,
                                                   const float* __restrict__ a,
                                                   const float* __restrict__ b,
                                                   const float* __restrict__ s0r,
                                                   const float* __restrict__ s0i,
                                                   unsigned short* __restrict__ scaled) {
    int bx = blockIdx.x;
    int chunk = bx >> 2;
    int rc = (bx & 3) * 256 + threadIdx.x;
    int r = rc >> 5, c = rc & 31;
    float e = expf(-fabsf(a[r]));
    float gr = e * cosf(b[c]);
    float gi = e * sinf(b[c]);
    float sr = s0r[rc], si = s0i[rc];
    // lookback over prior chunk transforms
    int j = 0;
    for (; j + 8 <= chunk; j += 8) {
        float4 buf[8];
#pragma unroll
        for (int u = 0; u < 8; ++u) buf[u] = ab4[(j + u) * RC + rc];
#pragma unroll
        for (int u = 0; u < 8; ++u) {
            float nsr = buf[u].z + buf[u].x * sr - buf[u].y * si;
            float nsi = buf[u].w + buf[u].x * si + buf[u].y * sr;
            sr = nsr; si = nsi;
        }
    }
    for (; j < chunk; ++j) {
        float4 ab = ab4[j * RC + rc];
        float nsr = ab.z + ab.x * sr - ab.y * si;
        float nsi = ab.w + ab.x * si + ab.y * sr;
        sr = nsr; si = nsi;
    }
    // rescan own chunk, emit features
    int t0 = chunk * CHUNK;
    for (int jj = 0; jj < CHUNK; ++jj) {
        int t = t0 + jj;
        float pre = tcabs[t * 64 + r] * tcabs[t * 64 + 32 + c];
        if (start[t]) {
            sr = pre; si = 0.f;
        } else {
            float nsr = pre + gr * sr - gi * si;
            float nsi =       gr * si + gi * sr;
            sr = nsr; si = nsi;
        }
        float m = sqrtf(sr * sr + si * si);
        float mag = log1pf(m);
        float f = (m > 0.f) ? (mag / m) : 0.f;
        scaled[(size_t)t * 2048 + rc]        = f2bf(si * f);
        scaled[(size_t)t * 2048 + 1024 + rc] = f2bf(sr * f);
    }
}

// ---------------------------------------------------------------------------
// Cm_partial[z][4096,N] = A[4096,Kz]bf16 @ B[N,Kz]bf16^T  (split-K partials)
// Tile 128x64, BK=32, 4 waves, named-scalar staging (proven round-4 loop).
// XCD-chunked logical-block swizzle: consecutive logical blocks (sharing an
// A-panel) land on the same XCD for L2 reuse. nwg must be divisible by 8.
template <int K, int N, int SPLITK>
__global__ __launch_bounds__(256) void gemm_bt_mfma(const unsigned short* __restrict__ A,
                                                    const unsigned short* __restrict__ B,
                                                    float* __restrict__ Cm) {
    __shared__ __align__(16) unsigned short As[128 * 32];
    __shared__ __align__(16) unsigned short Bs[64 * 32];
    const int tid = threadIdx.x;
    const int w = tid >> 6, lane = tid & 63;
    // XCD swizzle (performance-only remap; bijective since nwg % 8 == 0)
    const int nwg = gridDim.x * gridDim.y * gridDim.z;
    const int id = blockIdx.x + gridDim.x * (blockIdx.y + gridDim.y * blockIdx.z);
    const int lid = (id & 7) * (nwg >> 3) + (id >> 3);
    const int bxs = lid % gridDim.x;
    const int t2 = lid / gridDim.x;
    const int bys = t2 % gridDim.y;
    const int bzs = t2 / gridDim.y;
    const int bm = bys * 128, bn = bxs * 64;
    const int kbeg = bzs * (K / SPLITK);
    const int kend = kbeg + (K / SPLITK);
    const int wr = w >> 1, wc = w & 1;
    const int lr = lane >> 2;
    const int sl = lane & 3;
    const int swz_st = sl ^ ((lr >> 1) & 3);
    const size_t a_row0 = (size_t)(bm + w * 16 + lr);
    const size_t a_row1 = (size_t)(bm + 64 + w * 16 + lr);
    const size_t b_row  = (size_t)(bn + w * 16 + lr);
    const unsigned short* gA0 = A + a_row0 * K + sl * 8;
    const unsigned short* gA1 = A + a_row1 * K + sl * 8;
    const unsigned short* gB  = B + b_row  * K + sl * 8;
    const int wA0 = (w * 16 + lr) * 32 + swz_st * 8;
    const int wA1 = (64 + w * 16 + lr) * 32 + swz_st * 8;
    const int wB  = (w * 16 + lr) * 32 + swz_st * 8;
    const int fr = lane & 15, hi = lane >> 4;
    const int kslot = hi ^ ((fr >> 1) & 3);
    f32x4 acc[4][2] = {};

    uint4 va0 = *(const uint4*)(gA0 + kbeg);
    uint4 va1 = *(const uint4*)(gA1 + kbeg);
    uint4 vb  = *(const uint4*)(gB  + kbeg);
    for (int k0 = kbeg; k0 < kend; k0 += 32) {
        __syncthreads();
        *(uint4*)&As[wA0] = va0;
        *(uint4*)&As[wA1] = va1;
        *(uint4*)&Bs[wB]  = vb;
        __syncthreads();
        if (k0 + 32 < kend) {
            va0 = *(const uint4*)(gA0 + k0 + 32);
            va1 = *(const uint4*)(gA1 + k0 + 32);
            vb  = *(const uint4*)(gB  + k0 + 32);
        }
        bf16x8 af[4], bfv[2];
#pragma unroll
        for (int mi = 0; mi < 4; ++mi) {
            int row = wr * 64 + mi * 16 + fr;
            af[mi] = *(const bf16x8*)&As[row * 32 + kslot * 8];
        }
#pragma unroll
        for (int ni = 0; ni < 2; ++ni) {
            int row = wc * 32 + ni * 16 + fr;
            bfv[ni] = *(const bf16x8*)&Bs[row * 32 + kslot * 8];
        }
#pragma unroll
        for (int mi = 0; mi < 4; ++mi)
#pragma unroll
            for (int ni = 0; ni < 2; ++ni)
                acc[mi][ni] = __builtin_amdgcn_mfma_f32_16x16x32_bf16(
                    af[mi], bfv[ni], acc[mi][ni], 0, 0, 0);
    }
    // epilogue: C/D layout col=lane&15, row=(lane>>4)*4+reg  [m89]
    float* Cz = Cm + (size_t)bzs * TT * N;
    const int ccol0 = bn + wc * 32 + fr;
    const int crow0 = bm + wr * 64 + hi * 4;
#pragma unroll
    for (int ni = 0; ni < 2; ++ni) {
        int col = ccol0 + ni * 16;
#pragma unroll
        for (int mi = 0; mi < 4; ++mi)
#pragma unroll
            for (int q = 0; q < 4; ++q)
                Cz[(size_t)(crow0 + mi * 16 + q) * N + col] = acc[mi][ni][q];
    }
}

// ---------------------------------------------------------------------------
// Per-row: y = y0 + y1 + bias; LayerNorm + LeakyReLU.
__global__ __launch_bounds__(256) void ln_lrelu_kernel(const float* __restrict__ y0,
                                                       const float* __restrict__ y1,
                                                       const float* __restrict__ badd,
                                                       const float* __restrict__ g,
                                                       const float* __restrict__ be,
                                                       unsigned short* __restrict__ zb,
                                                       const float* __restrict__ res,
                                                       unsigned short* __restrict__ hbf,
                                                       float* __restrict__ fout) {
    int t = blockIdx.x;
    int tid = threadIdx.x;
    size_t base = (size_t)t * 512;
    float v0 = y0[base + tid] + y1[base + tid] + badd[tid];
    float v1 = y0[base + 256 + tid] + y1[base + 256 + tid] + badd[256 + tid];
    float s = v0 + v1, ss = v0 * v0 + v1 * v1;
#pragma unroll
    for (int o = 32; o > 0; o >>= 1) {
        s  += __shfl_down(s, o);
        ss += __shfl_down(ss, o);
    }
    __shared__ float sh[8];
    __shared__ float mrs[2];
    int wid = tid >> 6, lane = tid & 63;
    if (lane == 0) { sh[wid] = s; sh[4 + wid] = ss; }
    __syncthreads();
    if (tid == 0) {
        float S = sh[0] + sh[1] + sh[2] + sh[3];
        float SS = sh[4] + sh[5] + sh[6] + sh[7];
        float m = S * (1.f / 512.f);
        float var = SS * (1.f / 512.f) - m * m;
        mrs[0] = m;
        mrs[1] = rsqrtf(var + LN_EPS);
    }
    __syncthreads();
    float m = mrs[0], rs = mrs[1];
    float z0 = g[tid] * (v0 - m) * rs + be[tid];
    float z1 = g[256 + tid] * (v1 - m) * rs + be[256 + tid];
    z0 = (z0 > 0.f) ? z0 : NEG_SLOPE * z0;
    z1 = (z1 > 0.f) ? z1 : NEG_SLOPE * z1;
    if (zb)   { zb[base + tid] = f2bf(z0); zb[base + 256 + tid] = f2bf(z1); }
    if (hbf) {
        float h0 = (res ? res[base + tid] : 0.f) + z0;
        float h1 = (res ? res[base + 256 + tid] : 0.f) + z1;
        hbf[base + tid] = f2bf(h0);
        hbf[base + 256 + tid] = f2bf(h1);
    }
    if (fout) { fout[base + tid] = z0; fout[base + 256 + tid] = z1; }
}

// ---------------------------------------------------------------------------
extern "C" void kernel_launch(void* const* d_in, const int* in_sizes, int n_in,
                              void* d_out, int out_size, void* d_ws, size_t ws_size,
                              hipStream_t stream) {
    const float* x     = (const float*)d_in[0];
    const int*   start = (const int*)d_in[1];
    const float* s0r = (const float*)d_in[3];
    const float* s0i = (const float*)d_in[4];
    const float* Wt  = (const float*)d_in[5];
    const float* Wc  = (const float*)d_in[6];
    const float* a   = (const float*)d_in[7];
    const float* b   = (const float*)d_in[8];
    const float* W0  = (const float*)d_in[9];
    const float* b0  = (const float*)d_in[10];
    const float* g0  = (const float*)d_in[11];
    const float* be0 = (const float*)d_in[12];
    const float* W1  = (const float*)d_in[13];
    const float* b1  = (const float*)d_in[14];
    const float* g1  = (const float*)d_in[15];
    const float* be1 = (const float*)d_in[16];
    float* out = (float*)d_out;
    float* ws  = (float*)d_ws;

    // workspace layout (float-unit offsets, all 16B aligned)  ~50 MB
    float* p = ws;
    float* tcabs  = p; p += 262144;                  // [4096][64] f32 (invd folded)
    float4* ab4   = (float4*)p; p += 524288;         // [128][1024] float4
    unsigned short* scaled = (unsigned short*)p; p += 4194304;   // [4096][2048] bf16
    float* ybufp  = p; p += 4194304;                 // [2][4096][512] f32 partials
    unsigned short* zbuf_bf = (unsigned short*)p; p += 1048576;  // [4096][512] bf16
    unsigned short* x_bf    = (unsigned short*)p; p += 1048576;
    unsigned short* h_bf    = (unsigned short*)p; p += 1048576;
    unsigned short* Wtcbf   = (unsigned short*)p; p += 32768;    // [2][64][512] bf16
    unsigned short* W0bf    = (unsigned short*)p; p += 1048576;  // [2][512][2048] bf16
    unsigned short* W1bf    = (unsigned short*)p; p += 262144;   // [2][512][512] bf16

    setup_kernel<<<(NCV + NPK + 255) / 256, 256, 0, stream>>>(
        (const float4*)x, (const float4*)W0, (const float4*)W1, Wt, Wc,
        (ushort4*)x_bf, (ushort4*)W0bf, (ushort4*)W1bf, (ushort4*)Wtcbf);

    for (int i = 0; i < LL; ++i) {
        const unsigned short* hb = (i == 0) ? x_bf : h_bf;
        proj_denom_kernel<<<64, 256, 0, stream>>>(
            hb, Wtcbf + (size_t)i * 64 * 512, tcabs);
        scan_pass1<<<NCHUNK * RC / 256, 256, 0, stream>>>(
            tcabs, start, a + i * RR, b + i * CC, ab4);
        scan_pass2f<<<NCHUNK * 4, 256, 0, stream>>>(
            tcabs, ab4, start, a + i * RR, b + i * CC,
            s0r + i * RC, s0i + i * RC, scaled);
        gemm_bt_mfma<2048, 512, 2><<<dim3(8, 32, 2), 256, 0, stream>>>(
            scaled, W0bf + (size_t)i * 512 * 2048, ybufp);
        ln_lrelu_kernel<<<TT, 256, 0, stream>>>(
            ybufp, ybufp + (size_t)TT * 512, b0 + i * DD, g0 + i * DD, be0 + i * DD,
            zbuf_bf, nullptr, nullptr, nullptr);
        gemm_bt_mfma<512, 512, 2><<<dim3(8, 32, 2), 256, 0, stream>>>(
            zbuf_bf, W1bf + (size_t)i * 512 * 512, ybufp);
        ln_lrelu_kernel<<<TT, 256, 0, stream>>>(
            ybufp, ybufp + (size_t)TT * 512, b1 + i * DD, g1 + i * DD, be1 + i * DD,
            nullptr,
            (i < LL - 1) ? x : nullptr,
            (i < LL - 1) ? h_bf : nullptr,
            (i == LL - 1) ? out : nullptr);
    }
}